// Round 7
// baseline (1260.405 us; speedup 1.0000x reference)
//
#include <hip/hip_runtime.h>
#include <hip/hip_bf16.h>

typedef __hip_bfloat16 bf16;
typedef unsigned short u16;
typedef short v8s __attribute__((ext_vector_type(8)));
typedef u16   v8u __attribute__((ext_vector_type(8)));
typedef float v4f __attribute__((ext_vector_type(4)));

#define Hd 320
#define Wd 640
#define HWP (Hd*Wd)      // 204800
#define Bn 2
#define NCH1 188
#define HID 48
#define NBHW (Bn*HWP)    // 409600
#define CP 40            // LDS channel pitch (bf16 elems) per pixel (16B-aligned)
#define NPIX 324         // 18*18 halo pixels
#define XCH 192          // packed input channels (188 + 4 zero pad) = 24 slabs of 8
#define WIN 392          // fR window floats per half-row block (covers [x-67, x+3])

static __device__ __forceinline__ float b2f(bf16 v){ return __bfloat162float(v); }
static __device__ __forceinline__ bf16  f2b(float v){ return __float2bfloat16(v); }
static __device__ __forceinline__ u16 f2u(float v){ bf16 t = f2b(v); return *reinterpret_cast<u16*>(&t); }
static __device__ __forceinline__ float u2f(u16 u){ return __uint_as_float(((unsigned)u) << 16); }

// templated external-buffer load/store
template<typename T> static __device__ __forceinline__ float ld(const T* p, long i);
template<> __device__ __forceinline__ float ld<bf16>(const bf16* p, long i){ return b2f(p[i]); }
template<> __device__ __forceinline__ float ld<float>(const float* p, long i){ return p[i]; }
template<typename T> static __device__ __forceinline__ void stv(T* p, long i, float v);
template<> __device__ __forceinline__ void stv<bf16>(bf16* p, long i, float v){ p[i] = f2b(v); }
template<> __device__ __forceinline__ void stv<float>(float* p, long i, float v){ p[i] = v; }
template<typename T> struct want_flag;           // 0 = bf16, 1 = f32
template<> struct want_flag<bf16>  { static const int v = 0; };
template<> struct want_flag<float> { static const int v = 1; };

// ---------------- dtype probe (proven earlier) ----------------
__global__ void probe_k(const u16* __restrict__ dq, int* __restrict__ flag)
{
  __shared__ int cnt;
  if (threadIdx.x == 0) cnt = 0;
  __syncthreads();
  int bad = 0;
  for (int i = threadIdx.x; i < 2048; i += 256) {
    float v = __uint_as_float(((unsigned)dq[2*i]) << 16);
    if (!(fabsf(v) <= 65.f)) bad++;
  }
  atomicAdd(&cnt, bad);
  __syncthreads();
  if (threadIdx.x == 0) *flag = (cnt > 64) ? 1 : 0;
}

// packed channel p -> original conv1 cin (or -1 for zero pad)
// packed order: 0..63 fL | 64..127 fR_warp | 128..167 cost (i5-MAJOR: p = 128 + i5*8 + g,
//               orig cin = 148 + g*5 + i5) | 168..183 feat | 184 d | 185 sx | 186 sy |
//               187 conf | 188..191 zero
static __device__ __forceinline__ int pack2orig(int p)
{
  if (p < 128) return p;
  if (p < 168) { int idx = p - 128; int i5 = idx >> 3, g = idx & 7; return 148 + g*5 + i5; }
  if (p < 184) return 128 + (p - 168);
  if (p < 188) return 144 + (p - 184);
  return -1;
}

// ---------------- weight prepack: OIHW -> MFMA B-fragment order (bf16 bits) ----------------
// wf index: ((((chunk*9+tap)*3+nt)*64 + lane)*8 + j
// value = W[oc = nt*16 + (lane&15)][cin_packed = chunk*32 + (lane>>4)*8 + j][tap]
template<typename T>
__global__ void wconv_k(const int* __restrict__ flag,
                        const T* __restrict__ c1, const T* __restrict__ c2,
                        const T* __restrict__ c3,
                        const T* __restrict__ hdw, const T* __restrict__ hdb,
                        const T* __restrict__ hsxw, const T* __restrict__ hsxb,
                        const T* __restrict__ hsyw, const T* __restrict__ hsyb,
                        const T* __restrict__ hcw,  const T* __restrict__ hcb,
                        const T* __restrict__ hfw,  const T* __restrict__ hfb,
                        u16* __restrict__ wf1, u16* __restrict__ wf2,
                        u16* __restrict__ wf3, float* __restrict__ wh,
                        float* __restrict__ bh)
{
  if (*flag != want_flag<T>::v) return;
  int stride = gridDim.x * blockDim.x;
  int t0 = blockIdx.x * blockDim.x + threadIdx.x;
  const int N1 = 6*9*3*64*8;     // 82944
  for (int idx = t0; idx < N1; idx += stride) {
    int j = idx & 7; int lane = (idx >> 3) & 63; int rest = idx >> 9;
    int nt = rest % 3; rest /= 3; int tap = rest % 9; int chunk = rest / 9;
    int oc = nt*16 + (lane & 15);
    int cin = pack2orig(chunk*32 + (lane >> 4)*8 + j);
    float v = (cin >= 0) ? ld(c1, ((long)oc*NCH1 + cin)*9 + tap) : 0.f;
    wf1[idx] = f2u(v);
  }
  const int N2 = 2*9*3*64*8;     // 27648
  for (int idx = t0; idx < N2; idx += stride) {
    int j = idx & 7; int lane = (idx >> 3) & 63; int rest = idx >> 9;
    int nt = rest % 3; rest /= 3; int tap = rest % 9; int chunk = rest / 9;
    int oc = nt*16 + (lane & 15);
    int cin = chunk*32 + (lane >> 4)*8 + j;
    float v2 = 0.f, v3 = 0.f;
    if (cin < HID) {
      v2 = ld(c2, ((long)oc*HID + cin)*9 + tap);
      v3 = ld(c3, ((long)oc*HID + cin)*9 + tap);
    }
    wf2[idx] = f2u(v2);
    wf3[idx] = f2u(v3);
  }
  for (int i = t0; i < HID; i += stride) {
    wh[0*HID + i] = ld(hdw, i);
    wh[1*HID + i] = ld(hsxw, i);
    wh[2*HID + i] = ld(hsyw, i);
    wh[3*HID + i] = ld(hcw, i);
  }
  for (int i = t0; i < 16*HID; i += stride) wh[4*HID + i] = ld(hfw, i);
  if (t0 == 0) {
    bh[0] = ld(hdb,0); bh[1] = ld(hsxb,0); bh[2] = ld(hsyb,0); bh[3] = ld(hcb,0);
    for (int j = 0; j < 16; ++j) bh[4+j] = ld(hfb, j);
  }
}

// ---------------- build packed conv1 input: xpk[24 slabs][HWP][8] bf16, one batch ----------------
// grid (2, Hd), 320 threads: half-row blocks, one pixel per thread.
// - windowed fR stage (WIN floats, double-buffered) with async split: load regs ->
//   compute current g -> ds_write; one barrier per g.
// - 6-point lattice bilinear: the 5 disparity offsets are consecutive ints, so 6 shared
//   LDS reads + 5 lerps with one weight; clamped indices computed once per thread.
//   Border-equivalence: whenever clamping engages, both lattice points coincide.
template<typename T>
__global__ __launch_bounds__(320, 4) void build_x_k(
    const int* __restrict__ flag, int b,
    const T* __restrict__ dP, const T* __restrict__ sxP, const T* __restrict__ syP,
    const T* __restrict__ featP, const T* __restrict__ confP,
    const T* __restrict__ fL, const T* __restrict__ fR,
    u16* __restrict__ xpk)
{
  if (*flag != want_flag<T>::v) return;
  __shared__ float rowR[2][8][WIN];
  int y = blockIdx.y;
  int half = blockIdx.x;
  int tid = threadIdx.x;
  int x = half*320 + tid;
  int start = half ? 252 : 0;           // window [start, start+WIN)
  int valid = half ? 388 : 392;         // elements in [start, Wd)
  long rowoff = (long)y*Wd;
  long pix = rowoff + x;
  float dval = ld(dP, (long)b*HWP + pix);
  float base = (float)x - dval;
  float i0f = floorf(base);
  float w = base - i0f;
  int i0b = (int)i0f;
  // 6 clamped lattice indices (window-relative), computed once
  int idx0 = min(max(i0b - 2, start), Wd-1) - start;
  int idx1 = min(max(i0b - 1, start), Wd-1) - start;
  int idx2 = min(max(i0b    , start), Wd-1) - start;
  int idx3 = min(max(i0b + 1, start), Wd-1) - start;
  int idx4 = min(max(i0b + 2, start), Wd-1) - start;
  int idx5 = min(max(i0b + 3, start), Wd-1) - start;
  v8u cv0, cv1, cv2, cv3, cv4;          // cost: cvI5[g]

  // prologue: stage g=0 into buf 0
  for (int i = tid; i < 8*WIN; i += 320) {
    int cc = i / WIN, xx = i - cc*WIN;
    if (xx < valid)
      rowR[0][cc][xx] = ld(fR, ((long)(b*64 + cc))*HWP + rowoff + start + xx);
  }
  __syncthreads();

  #pragma unroll
  for (int g = 0; g < 8; ++g) {
    int bb = g & 1;
    // async-stage split: issue next-g loads into statically-indexed regs
    float stg[10];
    if (g < 7) {
      #pragma unroll
      for (int k = 0; k < 10; ++k) {
        int i = tid + k*320;
        int cc = i / WIN, xx = i - cc*WIN;
        stg[k] = (i < 8*WIN && xx < valid)
               ? ld(fR, ((long)(b*64 + (g+1)*8 + cc))*HWP + rowoff + start + xx) : 0.f;
      }
    }
    // compute current g from rowR[bb] (hides the staged loads' HBM latency)
    v8u flv, fwv;
    float a0=0.f, a1=0.f, a2=0.f, a3=0.f, a4=0.f;
    #pragma unroll
    for (int cc = 0; cc < 8; ++cc) {
      float fl = ld(fL, ((long)(b*64 + g*8 + cc))*HWP + pix);
      flv[cc] = f2u(fl);
      const float* rr = rowR[bb][cc];
      float r0 = rr[idx0], r1 = rr[idx1], r2 = rr[idx2];
      float r3 = rr[idx3], r4 = rr[idx4], r5 = rr[idx5];
      // s_i5 = r[4-i5]*(1-w) + r[5-i5]*w
      float s0 = r4 + w*(r5 - r4);
      float s1 = r3 + w*(r4 - r3);
      float s2v = r2 + w*(r3 - r2);
      float s3 = r1 + w*(r2 - r1);
      float s4 = r0 + w*(r1 - r0);
      a0 += fl*s0; a1 += fl*s1; a2 += fl*s2v; a3 += fl*s3; a4 += fl*s4;
      fwv[cc] = f2u(s2v);
    }
    *(v8u*)&xpk[((long)g*HWP + pix)*8]       = flv;   // slab g:   fL ch 8g..8g+8
    *(v8u*)&xpk[((long)(8 + g)*HWP + pix)*8] = fwv;   // slab 8+g: fw ch 8g..8g+8
    cv0[g] = f2u(a0*0.125f);
    cv1[g] = f2u(a1*0.125f);
    cv2[g] = f2u(a2*0.125f);
    cv3[g] = f2u(a3*0.125f);
    cv4[g] = f2u(a4*0.125f);
    // write-phase of the async stage (into the other buffer)
    if (g < 7) {
      #pragma unroll
      for (int k = 0; k < 10; ++k) {
        int i = tid + k*320;
        int cc = i / WIN, xx = i - cc*WIN;
        if (i < 8*WIN && xx < valid) rowR[bb ^ 1][cc][xx] = stg[k];
      }
    }
    __syncthreads();
  }
  // slabs 16..20: cost, i5-major (slab 16+i5 element g), matches prepack remap
  *(v8u*)&xpk[((long)16*HWP + pix)*8] = cv0;
  *(v8u*)&xpk[((long)17*HWP + pix)*8] = cv1;
  *(v8u*)&xpk[((long)18*HWP + pix)*8] = cv2;
  *(v8u*)&xpk[((long)19*HWP + pix)*8] = cv3;
  *(v8u*)&xpk[((long)20*HWP + pix)*8] = cv4;
  // slabs 21,22: feat 0..15
  #pragma unroll
  for (int k = 0; k < 2; ++k) {
    v8u fv;
    #pragma unroll
    for (int jj = 0; jj < 8; ++jj)
      fv[jj] = f2u(ld(featP, ((long)(b*16 + k*8 + jj))*HWP + pix));
    *(v8u*)&xpk[((long)(21 + k)*HWP + pix)*8] = fv;
  }
  // slab 23: d, sx, sy, conf, 4x zero pad
  {
    v8u sv8 = {0,0,0,0,0,0,0,0};
    sv8[0] = f2u(dval);
    sv8[1] = f2u(ld(sxP,  (long)b*HWP + pix));
    sv8[2] = f2u(ld(syP,  (long)b*HWP + pix));
    sv8[3] = f2u(ld(confP,(long)b*HWP + pix));
    *(v8u*)&xpk[((long)23*HWP + pix)*8] = sv8;
  }
}

// ---------------- shared conv epilogue: GN stats + pixel-major bf16 store ----------------
static __device__ __forceinline__ void conv_epilogue(
    v4f (*acc)[3], u16* lds, float (*sred)[2], u16* out48,
    float* st, int b, int x0, int y0, int tid)
{
  int lane = tid & 63, wave = tid >> 6;
  // per-oc sums over this wave's 16 pixels, then quad-reduce
  #pragma unroll
  for (int nt = 0; nt < 3; ++nt) {
    float s = 0.f, s2 = 0.f;
    #pragma unroll
    for (int mi = 0; mi < 4; ++mi)
      #pragma unroll
      for (int r = 0; r < 4; ++r) { float v = acc[mi][nt][r]; s += v; s2 += v*v; }
    s  += __shfl_xor(s, 16);  s2 += __shfl_xor(s2, 16);
    s  += __shfl_xor(s, 32);  s2 += __shfl_xor(s2, 32);
    if (lane < 16) {
      int g = (nt*16 + lane) / 6;
      atomicAdd(&sred[g][0], s);
      atomicAdd(&sred[g][1], s2);
    }
  }
  __syncthreads();   // all LDS mfma reads done; safe to repurpose lds
  #pragma unroll
  for (int mi = 0; mi < 4; ++mi) {
    int py = wave*4 + mi;
    #pragma unroll
    for (int nt = 0; nt < 3; ++nt) {
      int oc = nt*16 + (lane & 15);
      #pragma unroll
      for (int r = 0; r < 4; ++r) {
        int px = (lane >> 4)*4 + r;                 // D: row = quad*4+reg
        lds[oc*270 + py*16 + px] = f2u(acc[mi][nt][r]);
      }
    }
  }
  __syncthreads();
  {
    int pix = tid;                                   // one pixel per thread
    long base = ((long)(y0 + (pix>>4))*Wd + (x0 + (pix&15)))*HID;
    #pragma unroll
    for (int k = 0; k < 6; ++k) {
      v8u o;
      #pragma unroll
      for (int jj = 0; jj < 8; ++jj) o[jj] = lds[(k*8 + jj)*270 + pix];
      *(v8u*)&out48[base + k*8] = o;
    }
  }
  if (tid < 16) atomicAdd(&st[(b*8 + (tid>>1))*2 + (tid&1)], sred[tid>>1][tid&1]);
}

// ---------------- conv1 MFMA: packed 192ch (24 slabs of 8) -> 48, one batch ----------------
template<typename T>
__global__ __launch_bounds__(256) void conv1m_k(
    const int* __restrict__ flag, int b,
    const u16* __restrict__ xpk, const u16* __restrict__ wfrag,
    u16* __restrict__ out48, float* __restrict__ st)
{
  if (*flag != want_flag<T>::v) return;
  __shared__ __attribute__((aligned(16))) u16 lds[12960];   // stage [324 px][40] / epilogue [48][270]
  __shared__ float sred[8][2];
  int x0 = blockIdx.x*16, y0 = blockIdx.y*16;
  int tid = threadIdx.x, lane = tid & 63, wave = tid >> 6;
  if (tid < 16) ((float*)sred)[tid] = 0.f;
  v4f acc[4][3];
  #pragma unroll
  for (int mi = 0; mi < 4; ++mi)
    #pragma unroll
    for (int nt = 0; nt < 3; ++nt) acc[mi][nt] = (v4f){0.f,0.f,0.f,0.f};

  for (int ch = 0; ch < 6; ++ch) {
    __syncthreads();
    // stage 324 halo px x 32 ch: per pixel 4x16B from 4 slabs; within one
    // instruction each slab gets 16-consecutive-pixel (256B) contiguous runs
    for (int j = tid; j < 4*NPIX; j += 256) {
      int pix = j >> 2, q = j & 3;
      int r = pix / 18, cl = pix - r*18;
      int gy = y0 - 1 + r, gx = x0 - 1 + cl;
      v8u vals = {0,0,0,0,0,0,0,0};
      if (((unsigned)gy < Hd) & ((unsigned)gx < Wd))
        vals = *(const v8u*)&xpk[((long)(ch*4 + q)*HWP + (long)gy*Wd + gx)*8];
      *(v8u*)&lds[pix*CP + q*8] = vals;
    }
    __syncthreads();
    #pragma unroll
    for (int tap = 0; tap < 9; ++tap) {
      int dr = tap / 3, dc = tap - dr*3;
      v8s bf0 = *(const v8s*)&wfrag[((((ch*9+tap)*3 + 0)*64 + lane) << 3)];
      v8s bf1 = *(const v8s*)&wfrag[((((ch*9+tap)*3 + 1)*64 + lane) << 3)];
      v8s bf2 = *(const v8s*)&wfrag[((((ch*9+tap)*3 + 2)*64 + lane) << 3)];
      #pragma unroll
      for (int mi = 0; mi < 4; ++mi) {
        int py = wave*4 + mi;
        const v8s a = *(const v8s*)&lds[((py+dr)*18 + (lane&15) + dc)*CP + (lane>>4)*8];
        acc[mi][0] = __builtin_amdgcn_mfma_f32_16x16x32_bf16(a, bf0, acc[mi][0], 0, 0, 0);
        acc[mi][1] = __builtin_amdgcn_mfma_f32_16x16x32_bf16(a, bf1, acc[mi][1], 0, 0, 0);
        acc[mi][2] = __builtin_amdgcn_mfma_f32_16x16x32_bf16(a, bf2, acc[mi][2], 0, 0, 0);
      }
    }
  }
  __syncthreads();
  conv_epilogue(acc, lds, sred, out48, st, b, x0, y0, tid);
}

// ---------------- convH MFMA: pixel-major 48ch (GN+SiLU fused in staging) -> 48 ----------------
template<typename T>
__global__ __launch_bounds__(256) void convHm_k(
    const int* __restrict__ flag, int b,
    const u16* __restrict__ in48, const u16* __restrict__ wfrag,
    const float* __restrict__ stats, const T* __restrict__ gamma,
    const T* __restrict__ beta, u16* __restrict__ out48, float* __restrict__ st)
{
  if (*flag != want_flag<T>::v) return;
  __shared__ __attribute__((aligned(16))) u16 lds[12960];
  __shared__ float sred[8][2];
  __shared__ float sc[HID], of[HID];
  int x0 = blockIdx.x*16, y0 = blockIdx.y*16;
  int tid = threadIdx.x, lane = tid & 63, wave = tid >> 6;
  if (tid < 16) ((float*)sred)[tid] = 0.f;
  if (tid < HID) {
    int g = tid / 6;
    const float inv_n = 1.f / (6.f * HWP);
    float s  = stats[(b*8+g)*2+0];
    float s2 = stats[(b*8+g)*2+1];
    float m  = s * inv_n;
    float var = s2 * inv_n - m*m;
    float rs = rsqrtf(fmaxf(var, 0.f) + 1e-5f);
    float gm = ld(gamma, tid), bt = ld(beta, tid);
    sc[tid] = rs * gm;
    of[tid] = bt - m * rs * gm;
  }
  v4f acc[4][3];
  #pragma unroll
  for (int mi = 0; mi < 4; ++mi)
    #pragma unroll
    for (int nt = 0; nt < 3; ++nt) acc[mi][nt] = (v4f){0.f,0.f,0.f,0.f};

  for (int ch = 0; ch < 2; ++ch) {
    int cb = ch*32;
    __syncthreads();
    for (int j = tid; j < 4*NPIX; j += 256) {
      int pix = j >> 2, q = j & 3;
      int r = pix / 18, cl = pix - r*18;
      int gy = y0 - 1 + r, gx = x0 - 1 + cl;
      int c0 = cb + q*8;
      v8u vals = {0,0,0,0,0,0,0,0};
      if ((((unsigned)gy < Hd) & ((unsigned)gx < Wd)) && c0 < HID) {
        v8u raw = *(const v8u*)&in48[((long)gy*Wd + gx)*HID + c0];
        #pragma unroll
        for (int jj = 0; jj < 8; ++jj) {
          float v = u2f(raw[jj]) * sc[c0+jj] + of[c0+jj];
          vals[jj] = f2u(v / (1.f + __expf(-v)));   // SiLU; spatial zero-pad stays 0
        }
      }
      *(v8u*)&lds[pix*CP + q*8] = vals;
    }
    __syncthreads();
    #pragma unroll
    for (int tap = 0; tap < 9; ++tap) {
      int dr = tap / 3, dc = tap - dr*3;
      v8s bf0 = *(const v8s*)&wfrag[((((ch*9+tap)*3 + 0)*64 + lane) << 3)];
      v8s bf1 = *(const v8s*)&wfrag[((((ch*9+tap)*3 + 1)*64 + lane) << 3)];
      v8s bf2 = *(const v8s*)&wfrag[((((ch*9+tap)*3 + 2)*64 + lane) << 3)];
      #pragma unroll
      for (int mi = 0; mi < 4; ++mi) {
        int py = wave*4 + mi;
        const v8s a = *(const v8s*)&lds[((py+dr)*18 + (lane&15) + dc)*CP + (lane>>4)*8];
        acc[mi][0] = __builtin_amdgcn_mfma_f32_16x16x32_bf16(a, bf0, acc[mi][0], 0, 0, 0);
        acc[mi][1] = __builtin_amdgcn_mfma_f32_16x16x32_bf16(a, bf1, acc[mi][1], 0, 0, 0);
        acc[mi][2] = __builtin_amdgcn_mfma_f32_16x16x32_bf16(a, bf2, acc[mi][2], 0, 0, 0);
      }
    }
  }
  __syncthreads();
  conv_epilogue(acc, lds, sred, out48, st, b, x0, y0, tid);
}

// ---------------- heads: GN3+SiLU fused, 20 1x1 dots, output transforms; one batch ----------------
template<typename T>
__global__ __launch_bounds__(256) void heads_k(
    const int* __restrict__ flag, int b,
    const u16* __restrict__ h48, const float* __restrict__ st,
    const T* __restrict__ gamma, const T* __restrict__ beta,
    const float* __restrict__ wh, const float* __restrict__ bh,
    const T* __restrict__ dP, const T* __restrict__ sxP, const T* __restrict__ syP,
    const T* __restrict__ featP, const T* __restrict__ confP,
    T* __restrict__ out)
{
  if (*flag != want_flag<T>::v) return;
  __shared__ float sc[HID], of[HID];
  int p = blockIdx.x * 256 + threadIdx.x;
  long idx = (long)b*HWP + p;
  if (threadIdx.x < HID) {
    int c = threadIdx.x;
    int g = c / 6;
    const float inv_n = 1.f / (6.f * HWP);
    float s  = st[(b*8+g)*2+0];
    float s2 = st[(b*8+g)*2+1];
    float m  = s * inv_n;
    float var = s2 * inv_n - m*m;
    float rs = rsqrtf(fmaxf(var, 0.f) + 1e-5f);
    float gm = ld(gamma, c), bt = ld(beta, c);
    sc[c] = rs * gm;
    of[c] = bt - m * rs * gm;
  }
  __syncthreads();
  float hv[HID];
  #pragma unroll
  for (int k = 0; k < 6; ++k) {
    v8u h8 = *(const v8u*)&h48[(long)p*HID + k*8];
    #pragma unroll
    for (int jj = 0; jj < 8; ++jj) {
      int c = k*8 + jj;
      float v = u2f(h8[jj]) * sc[c] + of[c];
      hv[c] = v / (1.f + __expf(-v));
    }
  }
  float dot[20];
  #pragma unroll
  for (int r = 0; r < 20; ++r) {
    float a = bh[r];
    #pragma unroll
    for (int c = 0; c < HID; ++c) a += wh[r*HID + c] * hv[c];
    dot[r] = a;
  }
  float dval = ld(dP, idx);
  float xd = dot[0] + dval;
  float sp = fmaxf(xd, 0.f) + log1pf(__expf(-fabsf(xd)));
  stv(out, idx, sp);
  stv(out, NBHW + idx,    ld(sxP, idx) + 0.1f*dot[1]);
  stv(out, 2L*NBHW + idx, ld(syP, idx) + 0.1f*dot[2]);
  float cf = dot[3] + 2.f*ld(confP, idx) - 1.f;
  stv(out, 19L*NBHW + idx, 1.f/(1.f + __expf(-cf)));
  #pragma unroll
  for (int r = 0; r < 16; ++r) {
    long fi = ((long)(b*16 + r))*HWP + p;
    stv(out, 3L*NBHW + fi, ld(featP, fi) + dot[4+r]);
  }
}

extern "C" void kernel_launch(void* const* d_in, const int* in_sizes, int n_in,
                              void* d_out, int out_size, void* d_ws, size_t ws_size,
                              hipStream_t stream)
{
  // workspace (~98.6 MiB): xpk shares memory with h2 (disjoint lifetimes)
  char* ws = (char*)d_ws;
  size_t off = 0;
  u16* xpk = (u16*)(ws + off); off += (size_t)XCH*HWP*sizeof(u16);  // 78.6 MB (xpk, later h2)
  u16* h1  = (u16*)(ws + off); off += (size_t)HID*HWP*sizeof(u16);  // 19.66 MB (h1, later h3)
  u16* wf1 = (u16*)(ws + off); off += (size_t)6*9*3*64*8*sizeof(u16);
  u16* wf2 = (u16*)(ws + off); off += (size_t)2*9*3*64*8*sizeof(u16);
  u16* wf3 = (u16*)(ws + off); off += (size_t)2*9*3*64*8*sizeof(u16);
  float* wh = (float*)(ws + off); off += (size_t)20*HID*sizeof(float);
  float* bh = (float*)(ws + off); off += 32*sizeof(float);
  float* st = (float*)(ws + off); off += 96*sizeof(float);
  int* flag = (int*)(ws + off);   off += sizeof(int);
  u16* h2 = xpk;    // reuse: xpk dead after conv1 of each batch
  u16* h3 = h1;     // reuse: h1 dead after conv2

  hipMemsetAsync(st, 0, 96*sizeof(float), stream);
  probe_k<<<1, 256, 0, stream>>>((const u16*)d_in[0], flag);

  dim3 cgrid(Wd/16, Hd/16, 1);
  dim3 bgrid(2, Hd, 1);

  #define LAUNCH_ALL(T) do { \
    const T* dP    = (const T*)d_in[0]; \
    const T* sxP   = (const T*)d_in[1]; \
    const T* syP   = (const T*)d_in[2]; \
    const T* featP = (const T*)d_in[3]; \
    const T* confP = (const T*)d_in[4]; \
    const T* fL    = (const T*)d_in[5]; \
    const T* fR    = (const T*)d_in[6]; \
    wconv_k<T><<<320, 256, 0, stream>>>(flag, (const T*)d_in[7], (const T*)d_in[8], \
        (const T*)d_in[9], (const T*)d_in[16], (const T*)d_in[17], (const T*)d_in[18], \
        (const T*)d_in[19], (const T*)d_in[20], (const T*)d_in[21], (const T*)d_in[22], \
        (const T*)d_in[23], (const T*)d_in[24], (const T*)d_in[25], wf1, wf2, wf3, wh, bh); \
    for (int b = 0; b < Bn; ++b) { \
      build_x_k<T><<<bgrid, 320, 0, stream>>>(flag, b, dP, sxP, syP, featP, confP, fL, fR, xpk); \
      conv1m_k<T><<<cgrid, 256, 0, stream>>>(flag, b, xpk, wf1, h1, st + 0); \
      convHm_k<T><<<cgrid, 256, 0, stream>>>(flag, b, h1, wf2, st + 0,  (const T*)d_in[10], (const T*)d_in[11], h2, st + 32); \
      convHm_k<T><<<cgrid, 256, 0, stream>>>(flag, b, h2, wf3, st + 32, (const T*)d_in[12], (const T*)d_in[13], h3, st + 64); \
      heads_k<T><<<HWP/256, 256, 0, stream>>>(flag, b, h3, st + 64, (const T*)d_in[14], (const T*)d_in[15], \
          wh, bh, dP, sxP, syP, featP, confP, (T*)d_out); \
    } \
  } while (0)

  LAUNCH_ALL(bf16);
  LAUNCH_ALL(float);
  #undef LAUNCH_ALL
}

// Round 8
// 879.761 us; speedup vs baseline: 1.4327x; 1.4327x over previous
//
#include <hip/hip_runtime.h>
#include <hip/hip_bf16.h>

typedef __hip_bfloat16 bf16;
typedef unsigned short u16;
typedef short v8s __attribute__((ext_vector_type(8)));
typedef u16   v8u __attribute__((ext_vector_type(8)));
typedef float v4f __attribute__((ext_vector_type(4)));

#define Hd 320
#define Wd 640
#define HWP (Hd*Wd)      // 204800
#define Bn 2
#define NCH1 188
#define HID 48
#define NBHW (Bn*HWP)    // 409600
#define CP 40            // LDS channel pitch (bf16 elems) per pixel (16B-aligned)
#define NPIX 324         // 18*18 halo pixels
#define NSLAB 13         // xpk slabs of 8 ch: 0..7 fwarp, 8..12 cost (i5-major)

static __device__ __forceinline__ float b2f(bf16 v){ return __bfloat162float(v); }
static __device__ __forceinline__ bf16  f2b(float v){ return __float2bfloat16(v); }
static __device__ __forceinline__ u16 f2u(float v){ bf16 t = f2b(v); return *reinterpret_cast<u16*>(&t); }
static __device__ __forceinline__ float u2f(u16 u){ return __uint_as_float(((unsigned)u) << 16); }

// templated external-buffer load/store
template<typename T> static __device__ __forceinline__ float ld(const T* p, long i);
template<> __device__ __forceinline__ float ld<bf16>(const bf16* p, long i){ return b2f(p[i]); }
template<> __device__ __forceinline__ float ld<float>(const float* p, long i){ return p[i]; }
template<typename T> static __device__ __forceinline__ void stv(T* p, long i, float v);
template<> __device__ __forceinline__ void stv<bf16>(bf16* p, long i, float v){ p[i] = f2b(v); }
template<> __device__ __forceinline__ void stv<float>(float* p, long i, float v){ p[i] = v; }
template<typename T> struct want_flag;           // 0 = bf16, 1 = f32
template<> struct want_flag<bf16>  { static const int v = 0; };
template<> struct want_flag<float> { static const int v = 1; };

// ---------------- dtype probe (proven earlier) ----------------
__global__ void probe_k(const u16* __restrict__ dq, int* __restrict__ flag)
{
  __shared__ int cnt;
  if (threadIdx.x == 0) cnt = 0;
  __syncthreads();
  int bad = 0;
  for (int i = threadIdx.x; i < 2048; i += 256) {
    float v = __uint_as_float(((unsigned)dq[2*i]) << 16);
    if (!(fabsf(v) <= 65.f)) bad++;
  }
  atomicAdd(&cnt, bad);
  __syncthreads();
  if (threadIdx.x == 0) *flag = (cnt > 64) ? 1 : 0;
}

// packed channel p -> original conv1 cin (or -1 for zero pad)
// packed order: 0..63 fL | 64..127 fR_warp | 128..167 cost (i5-MAJOR: p = 128 + i5*8 + g,
//               orig cin = 148 + g*5 + i5) | 168..183 feat | 184 d | 185 sx | 186 sy |
//               187 conf | 188..191 zero
static __device__ __forceinline__ int pack2orig(int p)
{
  if (p < 128) return p;
  if (p < 168) { int idx = p - 128; int i5 = idx >> 3, g = idx & 7; return 148 + g*5 + i5; }
  if (p < 184) return 128 + (p - 168);
  if (p < 188) return 144 + (p - 184);
  return -1;
}

// ---------------- weight prepack: OIHW -> MFMA B-fragment order (bf16 bits) ----------------
// wf index: ((((chunk*9+tap)*3+nt)*64 + lane)*8 + j
// value = W[oc = nt*16 + (lane&15)][cin_packed = chunk*32 + (lane>>4)*8 + j][tap]
template<typename T>
__global__ void wconv_k(const int* __restrict__ flag,
                        const T* __restrict__ c1, const T* __restrict__ c2,
                        const T* __restrict__ c3,
                        const T* __restrict__ hdw, const T* __restrict__ hdb,
                        const T* __restrict__ hsxw, const T* __restrict__ hsxb,
                        const T* __restrict__ hsyw, const T* __restrict__ hsyb,
                        const T* __restrict__ hcw,  const T* __restrict__ hcb,
                        const T* __restrict__ hfw,  const T* __restrict__ hfb,
                        u16* __restrict__ wf1, u16* __restrict__ wf2,
                        u16* __restrict__ wf3, float* __restrict__ wh,
                        float* __restrict__ bh)
{
  if (*flag != want_flag<T>::v) return;
  int stride = gridDim.x * blockDim.x;
  int t0 = blockIdx.x * blockDim.x + threadIdx.x;
  const int N1 = 6*9*3*64*8;     // 82944
  for (int idx = t0; idx < N1; idx += stride) {
    int j = idx & 7; int lane = (idx >> 3) & 63; int rest = idx >> 9;
    int nt = rest % 3; rest /= 3; int tap = rest % 9; int chunk = rest / 9;
    int oc = nt*16 + (lane & 15);
    int cin = pack2orig(chunk*32 + (lane >> 4)*8 + j);
    float v = (cin >= 0) ? ld(c1, ((long)oc*NCH1 + cin)*9 + tap) : 0.f;
    wf1[idx] = f2u(v);
  }
  const int N2 = 2*9*3*64*8;     // 27648
  for (int idx = t0; idx < N2; idx += stride) {
    int j = idx & 7; int lane = (idx >> 3) & 63; int rest = idx >> 9;
    int nt = rest % 3; rest /= 3; int tap = rest % 9; int chunk = rest / 9;
    int oc = nt*16 + (lane & 15);
    int cin = chunk*32 + (lane >> 4)*8 + j;
    float v2 = 0.f, v3 = 0.f;
    if (cin < HID) {
      v2 = ld(c2, ((long)oc*HID + cin)*9 + tap);
      v3 = ld(c3, ((long)oc*HID + cin)*9 + tap);
    }
    wf2[idx] = f2u(v2);
    wf3[idx] = f2u(v3);
  }
  for (int i = t0; i < HID; i += stride) {
    wh[0*HID + i] = ld(hdw, i);
    wh[1*HID + i] = ld(hsxw, i);
    wh[2*HID + i] = ld(hsyw, i);
    wh[3*HID + i] = ld(hcw, i);
  }
  for (int i = t0; i < 16*HID; i += stride) wh[4*HID + i] = ld(hfw, i);
  if (t0 == 0) {
    bh[0] = ld(hdb,0); bh[1] = ld(hsxb,0); bh[2] = ld(hsyb,0); bh[3] = ld(hcb,0);
    for (int j = 0; j < 16; ++j) bh[4+j] = ld(hfb, j);
  }
}

// ---------------- build warp+corr only: xpk[13 slabs][HWP][8] bf16, one batch ----------------
// Slabs 0..7: fR_warp ch 8g..8g+7. Slabs 8..12: cost, i5-major (slab 8+i5, element g).
// fL / feat / scalars are NOT copied -- conv1 reads them directly from inputs.
// Round-6 structure (fastest measured): 640 thr/row, full-row fR stage, 2 barriers/g.
// 6-point lattice bilinear (consecutive offsets share lattice reads); nontemporal stores.
template<typename T>
__global__ __launch_bounds__(640) void build_x_k(
    const int* __restrict__ flag, int b,
    const T* __restrict__ dP,
    const T* __restrict__ fL, const T* __restrict__ fR,
    u16* __restrict__ xpk)
{
  if (*flag != want_flag<T>::v) return;
  __shared__ float rowR[8][Wd];
  int y = blockIdx.x;
  int x = threadIdx.x;                  // 0..639
  long rowoff = (long)y*Wd;
  long pix = rowoff + x;
  float dval = ld(dP, (long)b*HWP + pix);
  float base = (float)x - dval;
  float i0f = floorf(base);
  float w = base - i0f;
  int i0b = (int)i0f;
  // 6 clamped lattice indices, computed once per thread
  int idx0 = min(max(i0b - 2, 0), Wd-1);
  int idx1 = min(max(i0b - 1, 0), Wd-1);
  int idx2 = min(max(i0b    , 0), Wd-1);
  int idx3 = min(max(i0b + 1, 0), Wd-1);
  int idx4 = min(max(i0b + 2, 0), Wd-1);
  int idx5 = min(max(i0b + 3, 0), Wd-1);
  v8u cv0, cv1, cv2, cv3, cv4;          // cost: cvI5[g]

  #pragma unroll
  for (int g = 0; g < 8; ++g) {
    __syncthreads();
    #pragma unroll
    for (int cc = 0; cc < 8; ++cc)
      rowR[cc][x] = ld(fR, ((long)(b*64 + g*8 + cc))*HWP + rowoff + x);
    __syncthreads();
    v8u fwv;
    float a0=0.f, a1=0.f, a2=0.f, a3=0.f, a4=0.f;
    #pragma unroll
    for (int cc = 0; cc < 8; ++cc) {
      float fl = ld(fL, ((long)(b*64 + g*8 + cc))*HWP + pix);
      const float* rr = rowR[cc];
      float r0 = rr[idx0], r1 = rr[idx1], r2 = rr[idx2];
      float r3 = rr[idx3], r4 = rr[idx4], r5 = rr[idx5];
      // s_i5 = r[4-i5] + w*(r[5-i5]-r[4-i5])
      float s0 = r4 + w*(r5 - r4);
      float s1 = r3 + w*(r4 - r3);
      float s2v = r2 + w*(r3 - r2);
      float s3 = r1 + w*(r2 - r1);
      float s4 = r0 + w*(r1 - r0);
      a0 += fl*s0; a1 += fl*s1; a2 += fl*s2v; a3 += fl*s3; a4 += fl*s4;
      fwv[cc] = f2u(s2v);
    }
    __builtin_nontemporal_store(fwv, (v8u*)&xpk[((long)g*HWP + pix)*8]);  // slab g
    cv0[g] = f2u(a0*0.125f);
    cv1[g] = f2u(a1*0.125f);
    cv2[g] = f2u(a2*0.125f);
    cv3[g] = f2u(a3*0.125f);
    cv4[g] = f2u(a4*0.125f);
  }
  // slabs 8..12: cost, i5-major
  __builtin_nontemporal_store(cv0, (v8u*)&xpk[((long) 8*HWP + pix)*8]);
  __builtin_nontemporal_store(cv1, (v8u*)&xpk[((long) 9*HWP + pix)*8]);
  __builtin_nontemporal_store(cv2, (v8u*)&xpk[((long)10*HWP + pix)*8]);
  __builtin_nontemporal_store(cv3, (v8u*)&xpk[((long)11*HWP + pix)*8]);
  __builtin_nontemporal_store(cv4, (v8u*)&xpk[((long)12*HWP + pix)*8]);
}

// ---------------- shared conv epilogue: GN stats + pixel-major bf16 store ----------------
static __device__ __forceinline__ void conv_epilogue(
    v4f (*acc)[3], u16* lds, float (*sred)[2], u16* out48,
    float* st, int b, int x0, int y0, int tid)
{
  int lane = tid & 63, wave = tid >> 6;
  // per-oc sums over this wave's 16 pixels, then quad-reduce
  #pragma unroll
  for (int nt = 0; nt < 3; ++nt) {
    float s = 0.f, s2 = 0.f;
    #pragma unroll
    for (int mi = 0; mi < 4; ++mi)
      #pragma unroll
      for (int r = 0; r < 4; ++r) { float v = acc[mi][nt][r]; s += v; s2 += v*v; }
    s  += __shfl_xor(s, 16);  s2 += __shfl_xor(s2, 16);
    s  += __shfl_xor(s, 32);  s2 += __shfl_xor(s2, 32);
    if (lane < 16) {
      int g = (nt*16 + lane) / 6;
      atomicAdd(&sred[g][0], s);
      atomicAdd(&sred[g][1], s2);
    }
  }
  __syncthreads();   // all LDS mfma reads done; safe to repurpose lds
  #pragma unroll
  for (int mi = 0; mi < 4; ++mi) {
    int py = wave*4 + mi;
    #pragma unroll
    for (int nt = 0; nt < 3; ++nt) {
      int oc = nt*16 + (lane & 15);
      #pragma unroll
      for (int r = 0; r < 4; ++r) {
        int px = (lane >> 4)*4 + r;                 // D: row = quad*4+reg
        lds[oc*270 + py*16 + px] = f2u(acc[mi][nt][r]);
      }
    }
  }
  __syncthreads();
  {
    int pix = tid;                                   // one pixel per thread
    long base = ((long)(y0 + (pix>>4))*Wd + (x0 + (pix&15)))*HID;
    #pragma unroll
    for (int k = 0; k < 6; ++k) {
      v8u o;
      #pragma unroll
      for (int jj = 0; jj < 8; ++jj) o[jj] = lds[(k*8 + jj)*270 + pix];
      *(v8u*)&out48[base + k*8] = o;
    }
  }
  if (tid < 16) atomicAdd(&st[(b*8 + (tid>>1))*2 + (tid&1)], sred[tid>>1][tid&1]);
}

// ---------------- conv1 MFMA: fL/feat/scalars direct + xpk(warp,cost) -> 48, one batch ----------------
template<typename T>
__global__ __launch_bounds__(256) void conv1m_k(
    const int* __restrict__ flag, int b,
    const T* __restrict__ fL, const T* __restrict__ featP,
    const T* __restrict__ dP, const T* __restrict__ sxP, const T* __restrict__ syP,
    const T* __restrict__ confP,
    const u16* __restrict__ xpk, const u16* __restrict__ wfrag,
    u16* __restrict__ out48, float* __restrict__ st)
{
  if (*flag != want_flag<T>::v) return;
  __shared__ __attribute__((aligned(16))) u16 lds[12960];   // stage [324 px][40] / epilogue [48][270]
  __shared__ float sred[8][2];
  int x0 = blockIdx.x*16, y0 = blockIdx.y*16;
  int tid = threadIdx.x, lane = tid & 63, wave = tid >> 6;
  if (tid < 16) ((float*)sred)[tid] = 0.f;
  const T* fLb = fL + (long)b*64*HWP;
  v4f acc[4][3];
  #pragma unroll
  for (int mi = 0; mi < 4; ++mi)
    #pragma unroll
    for (int nt = 0; nt < 3; ++nt) acc[mi][nt] = (v4f){0.f,0.f,0.f,0.f};

  for (int ch = 0; ch < 6; ++ch) {
    __syncthreads();
    // stage 324 halo px x 32 ch; source depends on chunk (uniform branch):
    //  ch 0,1: fL planes (direct);  ch 2,3: fwarp slabs;  ch 4: cost slabs 8..11;
    //  ch 5: q0 = cost slab 12, q1/q2 = feat planes, q3 = d,sx,sy,conf + 4 zero
    for (int j = tid; j < 4*NPIX; j += 256) {
      int pix = j >> 2, q = j & 3;
      int r = pix / 18, cl = pix - r*18;
      int gy = y0 - 1 + r, gx = x0 - 1 + cl;
      bool inb = ((unsigned)gy < Hd) & ((unsigned)gx < Wd);
      long rowb = (long)gy*Wd + gx;
      v8u vals = {0,0,0,0,0,0,0,0};
      if (inb) {
        if (ch < 2) {
          int c0 = ch*32 + q*8;
          #pragma unroll
          for (int jj = 0; jj < 8; ++jj)
            vals[jj] = f2u(ld(fLb, (long)(c0+jj)*HWP + rowb));
        } else if (ch < 4) {
          vals = *(const v8u*)&xpk[((long)((ch-2)*4 + q)*HWP + rowb)*8];
        } else if (ch == 4) {
          vals = *(const v8u*)&xpk[((long)(8 + q)*HWP + rowb)*8];
        } else {
          if (q == 0) {
            vals = *(const v8u*)&xpk[((long)12*HWP + rowb)*8];
          } else if (q < 3) {
            #pragma unroll
            for (int jj = 0; jj < 8; ++jj)
              vals[jj] = f2u(ld(featP, ((long)(b*16 + (q-1)*8 + jj))*HWP + rowb));
          } else {
            vals[0] = f2u(ld(dP,   (long)b*HWP + rowb));
            vals[1] = f2u(ld(sxP,  (long)b*HWP + rowb));
            vals[2] = f2u(ld(syP,  (long)b*HWP + rowb));
            vals[3] = f2u(ld(confP,(long)b*HWP + rowb));
          }
        }
      }
      *(v8u*)&lds[pix*CP + q*8] = vals;
    }
    __syncthreads();
    #pragma unroll
    for (int tap = 0; tap < 9; ++tap) {
      int dr = tap / 3, dc = tap - dr*3;
      v8s bf0 = *(const v8s*)&wfrag[((((ch*9+tap)*3 + 0)*64 + lane) << 3)];
      v8s bf1 = *(const v8s*)&wfrag[((((ch*9+tap)*3 + 1)*64 + lane) << 3)];
      v8s bf2 = *(const v8s*)&wfrag[((((ch*9+tap)*3 + 2)*64 + lane) << 3)];
      #pragma unroll
      for (int mi = 0; mi < 4; ++mi) {
        int py = wave*4 + mi;
        const v8s a = *(const v8s*)&lds[((py+dr)*18 + (lane&15) + dc)*CP + (lane>>4)*8];
        acc[mi][0] = __builtin_amdgcn_mfma_f32_16x16x32_bf16(a, bf0, acc[mi][0], 0, 0, 0);
        acc[mi][1] = __builtin_amdgcn_mfma_f32_16x16x32_bf16(a, bf1, acc[mi][1], 0, 0, 0);
        acc[mi][2] = __builtin_amdgcn_mfma_f32_16x16x32_bf16(a, bf2, acc[mi][2], 0, 0, 0);
      }
    }
  }
  __syncthreads();
  conv_epilogue(acc, lds, sred, out48, st, b, x0, y0, tid);
}

// ---------------- convH MFMA: pixel-major 48ch (GN+SiLU fused in staging) -> 48 ----------------
template<typename T>
__global__ __launch_bounds__(256) void convHm_k(
    const int* __restrict__ flag, int b,
    const u16* __restrict__ in48, const u16* __restrict__ wfrag,
    const float* __restrict__ stats, const T* __restrict__ gamma,
    const T* __restrict__ beta, u16* __restrict__ out48, float* __restrict__ st)
{
  if (*flag != want_flag<T>::v) return;
  __shared__ __attribute__((aligned(16))) u16 lds[12960];
  __shared__ float sred[8][2];
  __shared__ float sc[HID], of[HID];
  int x0 = blockIdx.x*16, y0 = blockIdx.y*16;
  int tid = threadIdx.x, lane = tid & 63, wave = tid >> 6;
  if (tid < 16) ((float*)sred)[tid] = 0.f;
  if (tid < HID) {
    int g = tid / 6;
    const float inv_n = 1.f / (6.f * HWP);
    float s  = stats[(b*8+g)*2+0];
    float s2 = stats[(b*8+g)*2+1];
    float m  = s * inv_n;
    float var = s2 * inv_n - m*m;
    float rs = rsqrtf(fmaxf(var, 0.f) + 1e-5f);
    float gm = ld(gamma, tid), bt = ld(beta, tid);
    sc[tid] = rs * gm;
    of[tid] = bt - m * rs * gm;
  }
  v4f acc[4][3];
  #pragma unroll
  for (int mi = 0; mi < 4; ++mi)
    #pragma unroll
    for (int nt = 0; nt < 3; ++nt) acc[mi][nt] = (v4f){0.f,0.f,0.f,0.f};

  for (int ch = 0; ch < 2; ++ch) {
    int cb = ch*32;
    __syncthreads();
    for (int j = tid; j < 4*NPIX; j += 256) {
      int pix = j >> 2, q = j & 3;
      int r = pix / 18, cl = pix - r*18;
      int gy = y0 - 1 + r, gx = x0 - 1 + cl;
      int c0 = cb + q*8;
      v8u vals = {0,0,0,0,0,0,0,0};
      if ((((unsigned)gy < Hd) & ((unsigned)gx < Wd)) && c0 < HID) {
        v8u raw = *(const v8u*)&in48[((long)gy*Wd + gx)*HID + c0];
        #pragma unroll
        for (int jj = 0; jj < 8; ++jj) {
          float v = u2f(raw[jj]) * sc[c0+jj] + of[c0+jj];
          vals[jj] = f2u(v / (1.f + __expf(-v)));   // SiLU; spatial zero-pad stays 0
        }
      }
      *(v8u*)&lds[pix*CP + q*8] = vals;
    }
    __syncthreads();
    #pragma unroll
    for (int tap = 0; tap < 9; ++tap) {
      int dr = tap / 3, dc = tap - dr*3;
      v8s bf0 = *(const v8s*)&wfrag[((((ch*9+tap)*3 + 0)*64 + lane) << 3)];
      v8s bf1 = *(const v8s*)&wfrag[((((ch*9+tap)*3 + 1)*64 + lane) << 3)];
      v8s bf2 = *(const v8s*)&wfrag[((((ch*9+tap)*3 + 2)*64 + lane) << 3)];
      #pragma unroll
      for (int mi = 0; mi < 4; ++mi) {
        int py = wave*4 + mi;
        const v8s a = *(const v8s*)&lds[((py+dr)*18 + (lane&15) + dc)*CP + (lane>>4)*8];
        acc[mi][0] = __builtin_amdgcn_mfma_f32_16x16x32_bf16(a, bf0, acc[mi][0], 0, 0, 0);
        acc[mi][1] = __builtin_amdgcn_mfma_f32_16x16x32_bf16(a, bf1, acc[mi][1], 0, 0, 0);
        acc[mi][2] = __builtin_amdgcn_mfma_f32_16x16x32_bf16(a, bf2, acc[mi][2], 0, 0, 0);
      }
    }
  }
  __syncthreads();
  conv_epilogue(acc, lds, sred, out48, st, b, x0, y0, tid);
}

// ---------------- heads: GN3+SiLU fused, 20 1x1 dots, output transforms; one batch ----------------
template<typename T>
__global__ __launch_bounds__(256) void heads_k(
    const int* __restrict__ flag, int b,
    const u16* __restrict__ h48, const float* __restrict__ st,
    const T* __restrict__ gamma, const T* __restrict__ beta,
    const float* __restrict__ wh, const float* __restrict__ bh,
    const T* __restrict__ dP, const T* __restrict__ sxP, const T* __restrict__ syP,
    const T* __restrict__ featP, const T* __restrict__ confP,
    T* __restrict__ out)
{
  if (*flag != want_flag<T>::v) return;
  __shared__ float sc[HID], of[HID];
  int p = blockIdx.x * 256 + threadIdx.x;
  long idx = (long)b*HWP + p;
  if (threadIdx.x < HID) {
    int c = threadIdx.x;
    int g = c / 6;
    const float inv_n = 1.f / (6.f * HWP);
    float s  = st[(b*8+g)*2+0];
    float s2 = st[(b*8+g)*2+1];
    float m  = s * inv_n;
    float var = s2 * inv_n - m*m;
    float rs = rsqrtf(fmaxf(var, 0.f) + 1e-5f);
    float gm = ld(gamma, c), bt = ld(beta, c);
    sc[c] = rs * gm;
    of[c] = bt - m * rs * gm;
  }
  __syncthreads();
  float hv[HID];
  #pragma unroll
  for (int k = 0; k < 6; ++k) {
    v8u h8 = *(const v8u*)&h48[(long)p*HID + k*8];
    #pragma unroll
    for (int jj = 0; jj < 8; ++jj) {
      int c = k*8 + jj;
      float v = u2f(h8[jj]) * sc[c] + of[c];
      hv[c] = v / (1.f + __expf(-v));
    }
  }
  float dot[20];
  #pragma unroll
  for (int r = 0; r < 20; ++r) {
    float a = bh[r];
    #pragma unroll
    for (int c = 0; c < HID; ++c) a += wh[r*HID + c] * hv[c];
    dot[r] = a;
  }
  float dval = ld(dP, idx);
  float xd = dot[0] + dval;
  float sp = fmaxf(xd, 0.f) + log1pf(__expf(-fabsf(xd)));
  stv(out, idx, sp);
  stv(out, NBHW + idx,    ld(sxP, idx) + 0.1f*dot[1]);
  stv(out, 2L*NBHW + idx, ld(syP, idx) + 0.1f*dot[2]);
  float cf = dot[3] + 2.f*ld(confP, idx) - 1.f;
  stv(out, 19L*NBHW + idx, 1.f/(1.f + __expf(-cf)));
  #pragma unroll
  for (int r = 0; r < 16; ++r) {
    long fi = ((long)(b*16 + r))*HWP + p;
    stv(out, 3L*NBHW + fi, ld(featP, fi) + dot[4+r]);
  }
}

extern "C" void kernel_launch(void* const* d_in, const int* in_sizes, int n_in,
                              void* d_out, int out_size, void* d_ws, size_t ws_size,
                              hipStream_t stream)
{
  // workspace (~62.6 MiB): xpk (42.6 MB, warp+cost only) shares memory with h2
  char* ws = (char*)d_ws;
  size_t off = 0;
  u16* xpk = (u16*)(ws + off); off += (size_t)NSLAB*HWP*8*sizeof(u16); // 42.6 MB (xpk, later h2)
  u16* h1  = (u16*)(ws + off); off += (size_t)HID*HWP*sizeof(u16);     // 19.66 MB (h1, later h3)
  u16* wf1 = (u16*)(ws + off); off += (size_t)6*9*3*64*8*sizeof(u16);
  u16* wf2 = (u16*)(ws + off); off += (size_t)2*9*3*64*8*sizeof(u16);
  u16* wf3 = (u16*)(ws + off); off += (size_t)2*9*3*64*8*sizeof(u16);
  float* wh = (float*)(ws + off); off += (size_t)20*HID*sizeof(float);
  float* bh = (float*)(ws + off); off += 32*sizeof(float);
  float* st = (float*)(ws + off); off += 96*sizeof(float);
  int* flag = (int*)(ws + off);   off += sizeof(int);
  u16* h2 = xpk;    // reuse: xpk dead after conv1 of each batch
  u16* h3 = h1;     // reuse: h1 dead after conv2

  hipMemsetAsync(st, 0, 96*sizeof(float), stream);
  probe_k<<<1, 256, 0, stream>>>((const u16*)d_in[0], flag);

  dim3 cgrid(Wd/16, Hd/16, 1);

  #define LAUNCH_ALL(T) do { \
    const T* dP    = (const T*)d_in[0]; \
    const T* sxP   = (const T*)d_in[1]; \
    const T* syP   = (const T*)d_in[2]; \
    const T* featP = (const T*)d_in[3]; \
    const T* confP = (const T*)d_in[4]; \
    const T* fL    = (const T*)d_in[5]; \
    const T* fR    = (const T*)d_in[6]; \
    wconv_k<T><<<320, 256, 0, stream>>>(flag, (const T*)d_in[7], (const T*)d_in[8], \
        (const T*)d_in[9], (const T*)d_in[16], (const T*)d_in[17], (const T*)d_in[18], \
        (const T*)d_in[19], (const T*)d_in[20], (const T*)d_in[21], (const T*)d_in[22], \
        (const T*)d_in[23], (const T*)d_in[24], (const T*)d_in[25], wf1, wf2, wf3, wh, bh); \
    for (int b = 0; b < Bn; ++b) { \
      build_x_k<T><<<Hd, 640, 0, stream>>>(flag, b, dP, fL, fR, xpk); \
      conv1m_k<T><<<cgrid, 256, 0, stream>>>(flag, b, fL, featP, dP, sxP, syP, confP, xpk, wf1, h1, st + 0); \
      convHm_k<T><<<cgrid, 256, 0, stream>>>(flag, b, h1, wf2, st + 0,  (const T*)d_in[10], (const T*)d_in[11], h2, st + 32); \
      convHm_k<T><<<cgrid, 256, 0, stream>>>(flag, b, h2, wf3, st + 32, (const T*)d_in[12], (const T*)d_in[13], h3, st + 64); \
      heads_k<T><<<HWP/256, 256, 0, stream>>>(flag, b, h3, st + 64, (const T*)d_in[14], (const T*)d_in[15], \
          wh, bh, dP, sxP, syP, featP, confP, (T*)d_out); \
    } \
  } while (0)

  LAUNCH_ALL(bf16);
  LAUNCH_ALL(float);
  #undef LAUNCH_ALL
}

// Round 9
// 847.299 us; speedup vs baseline: 1.4876x; 1.0383x over previous
//
#include <hip/hip_runtime.h>
#include <hip/hip_bf16.h>

typedef __hip_bfloat16 bf16;
typedef unsigned short u16;
typedef short v8s __attribute__((ext_vector_type(8)));
typedef u16   v8u __attribute__((ext_vector_type(8)));
typedef float v4f __attribute__((ext_vector_type(4)));

#define Hd 320
#define Wd 640
#define HWP (Hd*Wd)      // 204800
#define Bn 2
#define NCH1 188
#define HID 48
#define NBHW (Bn*HWP)    // 409600
#define CP 40            // LDS channel pitch (bf16 elems) per pixel (16B-aligned)
#define NPIX 324         // 18*18 halo pixels
#define NSLAB 21         // xpk slabs of 8 ch: 0..7 fL, 8..15 fwarp, 16..20 cost (i5-major)

static __device__ __forceinline__ float b2f(bf16 v){ return __bfloat162float(v); }
static __device__ __forceinline__ bf16  f2b(float v){ return __float2bfloat16(v); }
static __device__ __forceinline__ u16 f2u(float v){ bf16 t = f2b(v); return *reinterpret_cast<u16*>(&t); }
static __device__ __forceinline__ float u2f(u16 u){ return __uint_as_float(((unsigned)u) << 16); }

// templated external-buffer load/store
template<typename T> static __device__ __forceinline__ float ld(const T* p, long i);
template<> __device__ __forceinline__ float ld<bf16>(const bf16* p, long i){ return b2f(p[i]); }
template<> __device__ __forceinline__ float ld<float>(const float* p, long i){ return p[i]; }
template<typename T> static __device__ __forceinline__ void stv(T* p, long i, float v);
template<> __device__ __forceinline__ void stv<bf16>(bf16* p, long i, float v){ p[i] = f2b(v); }
template<> __device__ __forceinline__ void stv<float>(float* p, long i, float v){ p[i] = v; }
template<typename T> struct want_flag;           // 0 = bf16, 1 = f32
template<> struct want_flag<bf16>  { static const int v = 0; };
template<> struct want_flag<float> { static const int v = 1; };

// ---------------- dtype probe (proven earlier) ----------------
__global__ void probe_k(const u16* __restrict__ dq, int* __restrict__ flag)
{
  __shared__ int cnt;
  if (threadIdx.x == 0) cnt = 0;
  __syncthreads();
  int bad = 0;
  for (int i = threadIdx.x; i < 2048; i += 256) {
    float v = __uint_as_float(((unsigned)dq[2*i]) << 16);
    if (!(fabsf(v) <= 65.f)) bad++;
  }
  atomicAdd(&cnt, bad);
  __syncthreads();
  if (threadIdx.x == 0) *flag = (cnt > 64) ? 1 : 0;
}

// packed channel p -> original conv1 cin (or -1 for zero pad)
// packed order: 0..63 fL | 64..127 fR_warp | 128..167 cost (i5-MAJOR: p = 128 + i5*8 + g,
//               orig cin = 148 + g*5 + i5) | 168..183 feat | 184 d | 185 sx | 186 sy |
//               187 conf | 188..191 zero
static __device__ __forceinline__ int pack2orig(int p)
{
  if (p < 128) return p;
  if (p < 168) { int idx = p - 128; int i5 = idx >> 3, g = idx & 7; return 148 + g*5 + i5; }
  if (p < 184) return 128 + (p - 168);
  if (p < 188) return 144 + (p - 184);
  return -1;
}

// ---------------- weight prepack: OIHW -> MFMA B-fragment order (bf16 bits) ----------------
// wf index: ((((chunk*9+tap)*3+nt)*64 + lane)*8 + j
// value = W[oc = nt*16 + (lane&15)][cin_packed = chunk*32 + (lane>>4)*8 + j][tap]
template<typename T>
__global__ void wconv_k(const int* __restrict__ flag,
                        const T* __restrict__ c1, const T* __restrict__ c2,
                        const T* __restrict__ c3,
                        const T* __restrict__ hdw, const T* __restrict__ hdb,
                        const T* __restrict__ hsxw, const T* __restrict__ hsxb,
                        const T* __restrict__ hsyw, const T* __restrict__ hsyb,
                        const T* __restrict__ hcw,  const T* __restrict__ hcb,
                        const T* __restrict__ hfw,  const T* __restrict__ hfb,
                        u16* __restrict__ wf1, u16* __restrict__ wf2,
                        u16* __restrict__ wf3, float* __restrict__ wh,
                        float* __restrict__ bh)
{
  if (*flag != want_flag<T>::v) return;
  int stride = gridDim.x * blockDim.x;
  int t0 = blockIdx.x * blockDim.x + threadIdx.x;
  const int N1 = 6*9*3*64*8;     // 82944
  for (int idx = t0; idx < N1; idx += stride) {
    int j = idx & 7; int lane = (idx >> 3) & 63; int rest = idx >> 9;
    int nt = rest % 3; rest /= 3; int tap = rest % 9; int chunk = rest / 9;
    int oc = nt*16 + (lane & 15);
    int cin = pack2orig(chunk*32 + (lane >> 4)*8 + j);
    float v = (cin >= 0) ? ld(c1, ((long)oc*NCH1 + cin)*9 + tap) : 0.f;
    wf1[idx] = f2u(v);
  }
  const int N2 = 2*9*3*64*8;     // 27648
  for (int idx = t0; idx < N2; idx += stride) {
    int j = idx & 7; int lane = (idx >> 3) & 63; int rest = idx >> 9;
    int nt = rest % 3; rest /= 3; int tap = rest % 9; int chunk = rest / 9;
    int oc = nt*16 + (lane & 15);
    int cin = chunk*32 + (lane >> 4)*8 + j;
    float v2 = 0.f, v3 = 0.f;
    if (cin < HID) {
      v2 = ld(c2, ((long)oc*HID + cin)*9 + tap);
      v3 = ld(c3, ((long)oc*HID + cin)*9 + tap);
    }
    wf2[idx] = f2u(v2);
    wf3[idx] = f2u(v3);
  }
  for (int i = t0; i < HID; i += stride) {
    wh[0*HID + i] = ld(hdw, i);
    wh[1*HID + i] = ld(hsxw, i);
    wh[2*HID + i] = ld(hsyw, i);
    wh[3*HID + i] = ld(hcw, i);
  }
  for (int i = t0; i < 16*HID; i += stride) wh[4*HID + i] = ld(hfw, i);
  if (t0 == 0) {
    bh[0] = ld(hdb,0); bh[1] = ld(hsxb,0); bh[2] = ld(hsyb,0); bh[3] = ld(hcb,0);
    for (int j = 0; j < 16; ++j) bh[4+j] = ld(hfb, j);
  }
}

// ---------------- build packed: xpk[21 slabs][HWP][8] bf16, one batch ----------------
// Slabs 0..7: fL ch 8g..8g+7 (bf16 copy -- kills conv1's scalar f32 staging).
// Slabs 8..15: fR_warp. Slabs 16..20: cost, i5-major. feat/scalars stay direct-read.
// Round-6 structure (fastest measured); 6-point lattice bilinear; nontemporal stores.
template<typename T>
__global__ __launch_bounds__(640) void build_x_k(
    const int* __restrict__ flag, int b,
    const T* __restrict__ dP,
    const T* __restrict__ fL, const T* __restrict__ fR,
    u16* __restrict__ xpk)
{
  if (*flag != want_flag<T>::v) return;
  __shared__ float rowR[8][Wd];
  int y = blockIdx.x;
  int x = threadIdx.x;                  // 0..639
  long rowoff = (long)y*Wd;
  long pix = rowoff + x;
  float dval = ld(dP, (long)b*HWP + pix);
  float base = (float)x - dval;
  float i0f = floorf(base);
  float w = base - i0f;
  int i0b = (int)i0f;
  // 6 clamped lattice indices, computed once per thread
  int idx0 = min(max(i0b - 2, 0), Wd-1);
  int idx1 = min(max(i0b - 1, 0), Wd-1);
  int idx2 = min(max(i0b    , 0), Wd-1);
  int idx3 = min(max(i0b + 1, 0), Wd-1);
  int idx4 = min(max(i0b + 2, 0), Wd-1);
  int idx5 = min(max(i0b + 3, 0), Wd-1);
  v8u cv0, cv1, cv2, cv3, cv4;          // cost: cvI5[g]

  #pragma unroll
  for (int g = 0; g < 8; ++g) {
    __syncthreads();
    #pragma unroll
    for (int cc = 0; cc < 8; ++cc)
      rowR[cc][x] = ld(fR, ((long)(b*64 + g*8 + cc))*HWP + rowoff + x);
    __syncthreads();
    v8u flv, fwv;
    float a0=0.f, a1=0.f, a2=0.f, a3=0.f, a4=0.f;
    #pragma unroll
    for (int cc = 0; cc < 8; ++cc) {
      float fl = ld(fL, ((long)(b*64 + g*8 + cc))*HWP + pix);
      flv[cc] = f2u(fl);
      const float* rr = rowR[cc];
      float r0 = rr[idx0], r1 = rr[idx1], r2 = rr[idx2];
      float r3 = rr[idx3], r4 = rr[idx4], r5 = rr[idx5];
      // s_i5 = r[4-i5] + w*(r[5-i5]-r[4-i5])
      float s0 = r4 + w*(r5 - r4);
      float s1 = r3 + w*(r4 - r3);
      float s2v = r2 + w*(r3 - r2);
      float s3 = r1 + w*(r2 - r1);
      float s4 = r0 + w*(r1 - r0);
      a0 += fl*s0; a1 += fl*s1; a2 += fl*s2v; a3 += fl*s3; a4 += fl*s4;
      fwv[cc] = f2u(s2v);
    }
    __builtin_nontemporal_store(flv, (v8u*)&xpk[((long)g*HWP + pix)*8]);       // slab g: fL
    __builtin_nontemporal_store(fwv, (v8u*)&xpk[((long)(8 + g)*HWP + pix)*8]); // slab 8+g: fwarp
    cv0[g] = f2u(a0*0.125f);
    cv1[g] = f2u(a1*0.125f);
    cv2[g] = f2u(a2*0.125f);
    cv3[g] = f2u(a3*0.125f);
    cv4[g] = f2u(a4*0.125f);
  }
  // slabs 16..20: cost, i5-major
  __builtin_nontemporal_store(cv0, (v8u*)&xpk[((long)16*HWP + pix)*8]);
  __builtin_nontemporal_store(cv1, (v8u*)&xpk[((long)17*HWP + pix)*8]);
  __builtin_nontemporal_store(cv2, (v8u*)&xpk[((long)18*HWP + pix)*8]);
  __builtin_nontemporal_store(cv3, (v8u*)&xpk[((long)19*HWP + pix)*8]);
  __builtin_nontemporal_store(cv4, (v8u*)&xpk[((long)20*HWP + pix)*8]);
}

// ---------------- shared conv epilogue: GN stats + pixel-major bf16 store ----------------
static __device__ __forceinline__ void conv_epilogue(
    v4f (*acc)[3], u16* lds, float (*sred)[2], u16* out48,
    float* st, int b, int x0, int y0, int tid)
{
  int lane = tid & 63, wave = tid >> 6;
  // per-oc sums over this wave's 16 pixels, then quad-reduce
  #pragma unroll
  for (int nt = 0; nt < 3; ++nt) {
    float s = 0.f, s2 = 0.f;
    #pragma unroll
    for (int mi = 0; mi < 4; ++mi)
      #pragma unroll
      for (int r = 0; r < 4; ++r) { float v = acc[mi][nt][r]; s += v; s2 += v*v; }
    s  += __shfl_xor(s, 16);  s2 += __shfl_xor(s2, 16);
    s  += __shfl_xor(s, 32);  s2 += __shfl_xor(s2, 32);
    if (lane < 16) {
      int g = (nt*16 + lane) / 6;
      atomicAdd(&sred[g][0], s);
      atomicAdd(&sred[g][1], s2);
    }
  }
  __syncthreads();   // all LDS mfma reads done; safe to repurpose lds
  #pragma unroll
  for (int mi = 0; mi < 4; ++mi) {
    int py = wave*4 + mi;
    #pragma unroll
    for (int nt = 0; nt < 3; ++nt) {
      int oc = nt*16 + (lane & 15);
      #pragma unroll
      for (int r = 0; r < 4; ++r) {
        int px = (lane >> 4)*4 + r;                 // D: row = quad*4+reg
        lds[oc*270 + py*16 + px] = f2u(acc[mi][nt][r]);
      }
    }
  }
  __syncthreads();
  {
    int pix = tid;                                   // one pixel per thread
    long base = ((long)(y0 + (pix>>4))*Wd + (x0 + (pix&15)))*HID;
    #pragma unroll
    for (int k = 0; k < 6; ++k) {
      v8u o;
      #pragma unroll
      for (int jj = 0; jj < 8; ++jj) o[jj] = lds[(k*8 + jj)*270 + pix];
      *(v8u*)&out48[base + k*8] = o;
    }
  }
  if (tid < 16) atomicAdd(&st[(b*8 + (tid>>1))*2 + (tid&1)], sred[tid>>1][tid&1]);
}

// ---------------- conv1 MFMA: all-vector slab staging + T14 prefetch -> 48, one batch ----------------
// chunk ch<5: slabs ch*4+q; chunk 5: q0 = slab 20 (cost i5=4), q1/q2 = feat, q3 = scalars.
template<typename T>
__global__ __launch_bounds__(256) void conv1m_k(
    const int* __restrict__ flag, int b,
    const T* __restrict__ featP,
    const T* __restrict__ dP, const T* __restrict__ sxP, const T* __restrict__ syP,
    const T* __restrict__ confP,
    const u16* __restrict__ xpk, const u16* __restrict__ wfrag,
    u16* __restrict__ out48, float* __restrict__ st)
{
  if (*flag != want_flag<T>::v) return;
  __shared__ __attribute__((aligned(16))) u16 lds[12960];   // stage [324 px][40] / epilogue [48][270]
  __shared__ float sred[8][2];
  int x0 = blockIdx.x*16, y0 = blockIdx.y*16;
  int tid = threadIdx.x, lane = tid & 63, wave = tid >> 6;
  if (tid < 16) ((float*)sred)[tid] = 0.f;
  v4f acc[4][3];
  #pragma unroll
  for (int mi = 0; mi < 4; ++mi)
    #pragma unroll
    for (int nt = 0; nt < 3; ++nt) acc[mi][nt] = (v4f){0.f,0.f,0.f,0.f};

  // prologue: stage chunk 0 (fL slabs 0..3) directly
  #pragma unroll
  for (int k = 0; k < 6; ++k) {
    int j = tid + k*256;
    if (j < 4*NPIX) {
      int pix = j >> 2, q = j & 3;
      int r = pix / 18, cl = pix - r*18;
      int gy = y0 - 1 + r, gx = x0 - 1 + cl;
      v8u vals = {0,0,0,0,0,0,0,0};
      if (((unsigned)gy < Hd) & ((unsigned)gx < Wd))
        vals = *(const v8u*)&xpk[((long)q*HWP + (long)gy*Wd + gx)*8];
      *(v8u*)&lds[pix*CP + q*8] = vals;
    }
  }

  v8u pf0, pf1, pf2, pf3, pf4, pf5;

#define PF_LOAD(k, dst) do { \
    dst = (v8u){0,0,0,0,0,0,0,0}; \
    int j = tid + k*256; \
    if (j < 4*NPIX) { \
      int pix = j >> 2, q = j & 3; \
      int r = pix / 18, cl = pix - r*18; \
      int gy = y0 - 1 + r, gx = x0 - 1 + cl; \
      if ((((unsigned)gy < Hd) & ((unsigned)gx < Wd)) && (nch < 5 || q == 0)) \
        dst = *(const v8u*)&xpk[((long)(nch < 5 ? nch*4 + q : 20)*HWP + (long)gy*Wd + gx)*8]; \
    } } while (0)

#define PF_WRITE(k, src) do { \
    int j = tid + k*256; \
    if (j < 4*NPIX) { \
      int pix = j >> 2, q = j & 3; \
      int r = pix / 18, cl = pix - r*18; \
      int gy = y0 - 1 + r, gx = x0 - 1 + cl; \
      bool inb = ((unsigned)gy < Hd) & ((unsigned)gx < Wd); \
      long rowb = (long)gy*Wd + gx; \
      v8u vals = src; \
      if (nch == 5 && inb) { \
        if (q == 1 || q == 2) { \
          _Pragma("unroll") \
          for (int jj = 0; jj < 8; ++jj) \
            vals[jj] = f2u(ld(featP, ((long)(b*16 + (q-1)*8 + jj))*HWP + rowb)); \
        } else if (q == 3) { \
          vals[0] = f2u(ld(dP,   (long)b*HWP + rowb)); \
          vals[1] = f2u(ld(sxP,  (long)b*HWP + rowb)); \
          vals[2] = f2u(ld(syP,  (long)b*HWP + rowb)); \
          vals[3] = f2u(ld(confP,(long)b*HWP + rowb)); \
        } } \
      *(v8u*)&lds[pix*CP + q*8] = vals; \
    } } while (0)

  for (int ch = 0; ch < 6; ++ch) {
    int nch = ch + 1;
    __syncthreads();                       // staged LDS for ch is ready
    if (nch < 6) {                         // T14: issue next chunk's loads early
      PF_LOAD(0, pf0); PF_LOAD(1, pf1); PF_LOAD(2, pf2);
      PF_LOAD(3, pf3); PF_LOAD(4, pf4); PF_LOAD(5, pf5);
    }
    #pragma unroll
    for (int tap = 0; tap < 9; ++tap) {
      int dr = tap / 3, dc = tap - dr*3;
      v8s bf0 = *(const v8s*)&wfrag[((((ch*9+tap)*3 + 0)*64 + lane) << 3)];
      v8s bf1 = *(const v8s*)&wfrag[((((ch*9+tap)*3 + 1)*64 + lane) << 3)];
      v8s bf2 = *(const v8s*)&wfrag[((((ch*9+tap)*3 + 2)*64 + lane) << 3)];
      #pragma unroll
      for (int mi = 0; mi < 4; ++mi) {
        int py = wave*4 + mi;
        const v8s a = *(const v8s*)&lds[((py+dr)*18 + (lane&15) + dc)*CP + (lane>>4)*8];
        acc[mi][0] = __builtin_amdgcn_mfma_f32_16x16x32_bf16(a, bf0, acc[mi][0], 0, 0, 0);
        acc[mi][1] = __builtin_amdgcn_mfma_f32_16x16x32_bf16(a, bf1, acc[mi][1], 0, 0, 0);
        acc[mi][2] = __builtin_amdgcn_mfma_f32_16x16x32_bf16(a, bf2, acc[mi][2], 0, 0, 0);
      }
    }
    __syncthreads();                       // all MFMA LDS reads for ch done
    if (nch < 6) {                         // write-phase of the prefetch
      PF_WRITE(0, pf0); PF_WRITE(1, pf1); PF_WRITE(2, pf2);
      PF_WRITE(3, pf3); PF_WRITE(4, pf4); PF_WRITE(5, pf5);
    }
  }
#undef PF_LOAD
#undef PF_WRITE
  conv_epilogue(acc, lds, sred, out48, st, b, x0, y0, tid);
}

// ---------------- convH MFMA: pixel-major 48ch, T14 prefetch, GN+SiLU in write phase ----------------
template<typename T>
__global__ __launch_bounds__(256) void convHm_k(
    const int* __restrict__ flag, int b,
    const u16* __restrict__ in48, const u16* __restrict__ wfrag,
    const float* __restrict__ stats, const T* __restrict__ gamma,
    const T* __restrict__ beta, u16* __restrict__ out48, float* __restrict__ st)
{
  if (*flag != want_flag<T>::v) return;
  __shared__ __attribute__((aligned(16))) u16 lds[12960];
  __shared__ float sred[8][2];
  __shared__ float sc[HID], of[HID];
  int x0 = blockIdx.x*16, y0 = blockIdx.y*16;
  int tid = threadIdx.x, lane = tid & 63, wave = tid >> 6;
  if (tid < 16) ((float*)sred)[tid] = 0.f;
  if (tid < HID) {
    int g = tid / 6;
    const float inv_n = 1.f / (6.f * HWP);
    float s  = stats[(b*8+g)*2+0];
    float s2 = stats[(b*8+g)*2+1];
    float m  = s * inv_n;
    float var = s2 * inv_n - m*m;
    float rs = rsqrtf(fmaxf(var, 0.f) + 1e-5f);
    float gm = ld(gamma, tid), bt = ld(beta, tid);
    sc[tid] = rs * gm;
    of[tid] = bt - m * rs * gm;
  }
  v4f acc[4][3];
  #pragma unroll
  for (int mi = 0; mi < 4; ++mi)
    #pragma unroll
    for (int nt = 0; nt < 3; ++nt) acc[mi][nt] = (v4f){0.f,0.f,0.f,0.f};

  v8u pf0, pf1, pf2, pf3, pf4, pf5;

#define HPF_LOAD(k, dst, cb) do { \
    dst = (v8u){0,0,0,0,0,0,0,0}; \
    int j = tid + k*256; \
    if (j < 4*NPIX) { \
      int pix = j >> 2, q = j & 3; \
      int r = pix / 18, cl = pix - r*18; \
      int gy = y0 - 1 + r, gx = x0 - 1 + cl; \
      int c0 = (cb) + q*8; \
      if ((((unsigned)gy < Hd) & ((unsigned)gx < Wd)) && c0 < HID) \
        dst = *(const v8u*)&in48[((long)gy*Wd + gx)*HID + c0]; \
    } } while (0)

#define HPF_WRITE(k, src, cb) do { \
    int j = tid + k*256; \
    if (j < 4*NPIX) { \
      int pix = j >> 2, q = j & 3; \
      int r = pix / 18, cl = pix - r*18; \
      int gy = y0 - 1 + r, gx = x0 - 1 + cl; \
      int c0 = (cb) + q*8; \
      v8u vals = {0,0,0,0,0,0,0,0}; \
      if ((((unsigned)gy < Hd) & ((unsigned)gx < Wd)) && c0 < HID) { \
        _Pragma("unroll") \
        for (int jj = 0; jj < 8; ++jj) { \
          float v = u2f(src[jj]) * sc[c0+jj] + of[c0+jj]; \
          vals[jj] = f2u(v / (1.f + __expf(-v))); \
        } } \
      *(v8u*)&lds[pix*CP + q*8] = vals; \
    } } while (0)

#define HMFMA(ch) do { \
    _Pragma("unroll") \
    for (int tap = 0; tap < 9; ++tap) { \
      int dr = tap / 3, dc = tap - dr*3; \
      v8s bf0 = *(const v8s*)&wfrag[(((((ch)*9+tap)*3 + 0)*64 + lane) << 3)]; \
      v8s bf1 = *(const v8s*)&wfrag[(((((ch)*9+tap)*3 + 1)*64 + lane) << 3)]; \
      v8s bf2 = *(const v8s*)&wfrag[(((((ch)*9+tap)*3 + 2)*64 + lane) << 3)]; \
      _Pragma("unroll") \
      for (int mi = 0; mi < 4; ++mi) { \
        int py = wave*4 + mi; \
        const v8s a = *(const v8s*)&lds[((py+dr)*18 + (lane&15) + dc)*CP + (lane>>4)*8]; \
        acc[mi][0] = __builtin_amdgcn_mfma_f32_16x16x32_bf16(a, bf0, acc[mi][0], 0, 0, 0); \
        acc[mi][1] = __builtin_amdgcn_mfma_f32_16x16x32_bf16(a, bf1, acc[mi][1], 0, 0, 0); \
        acc[mi][2] = __builtin_amdgcn_mfma_f32_16x16x32_bf16(a, bf2, acc[mi][2], 0, 0, 0); \
      } } } while (0)

  // issue ch0 raw loads (independent of sc/of)
  HPF_LOAD(0, pf0, 0); HPF_LOAD(1, pf1, 0); HPF_LOAD(2, pf2, 0);
  HPF_LOAD(3, pf3, 0); HPF_LOAD(4, pf4, 0); HPF_LOAD(5, pf5, 0);
  __syncthreads();                          // sc/of ready
  HPF_WRITE(0, pf0, 0); HPF_WRITE(1, pf1, 0); HPF_WRITE(2, pf2, 0);
  HPF_WRITE(3, pf3, 0); HPF_WRITE(4, pf4, 0); HPF_WRITE(5, pf5, 0);
  // issue ch1 raw loads
  HPF_LOAD(0, pf0, 32); HPF_LOAD(1, pf1, 32); HPF_LOAD(2, pf2, 32);
  HPF_LOAD(3, pf3, 32); HPF_LOAD(4, pf4, 32); HPF_LOAD(5, pf5, 32);
  __syncthreads();                          // LDS ch0 ready
  HMFMA(0);
  __syncthreads();                          // MFMA ch0 reads done
  HPF_WRITE(0, pf0, 32); HPF_WRITE(1, pf1, 32); HPF_WRITE(2, pf2, 32);
  HPF_WRITE(3, pf3, 32); HPF_WRITE(4, pf4, 32); HPF_WRITE(5, pf5, 32);
  __syncthreads();                          // LDS ch1 ready
  HMFMA(1);
#undef HPF_LOAD
#undef HPF_WRITE
#undef HMFMA
  __syncthreads();
  conv_epilogue(acc, lds, sred, out48, st, b, x0, y0, tid);
}

// ---------------- heads: GN3+SiLU fused, 20 1x1 dots, output transforms; one batch ----------------
template<typename T>
__global__ __launch_bounds__(256) void heads_k(
    const int* __restrict__ flag, int b,
    const u16* __restrict__ h48, const float* __restrict__ st,
    const T* __restrict__ gamma, const T* __restrict__ beta,
    const float* __restrict__ wh, const float* __restrict__ bh,
    const T* __restrict__ dP, const T* __restrict__ sxP, const T* __restrict__ syP,
    const T* __restrict__ featP, const T* __restrict__ confP,
    T* __restrict__ out)
{
  if (*flag != want_flag<T>::v) return;
  __shared__ float sc[HID], of[HID];
  int p = blockIdx.x * 256 + threadIdx.x;
  long idx = (long)b*HWP + p;
  if (threadIdx.x < HID) {
    int c = threadIdx.x;
    int g = c / 6;
    const float inv_n = 1.f / (6.f * HWP);
    float s  = st[(b*8+g)*2+0];
    float s2 = st[(b*8+g)*2+1];
    float m  = s * inv_n;
    float var = s2 * inv_n - m*m;
    float rs = rsqrtf(fmaxf(var, 0.f) + 1e-5f);
    float gm = ld(gamma, c), bt = ld(beta, c);
    sc[c] = rs * gm;
    of[c] = bt - m * rs * gm;
  }
  __syncthreads();
  float hv[HID];
  #pragma unroll
  for (int k = 0; k < 6; ++k) {
    v8u h8 = *(const v8u*)&h48[(long)p*HID + k*8];
    #pragma unroll
    for (int jj = 0; jj < 8; ++jj) {
      int c = k*8 + jj;
      float v = u2f(h8[jj]) * sc[c] + of[c];
      hv[c] = v / (1.f + __expf(-v));
    }
  }
  float dot[20];
  #pragma unroll
  for (int r = 0; r < 20; ++r) {
    float a = bh[r];
    #pragma unroll
    for (int c = 0; c < HID; ++c) a += wh[r*HID + c] * hv[c];
    dot[r] = a;
  }
  float dval = ld(dP, idx);
  float xd = dot[0] + dval;
  float sp = fmaxf(xd, 0.f) + log1pf(__expf(-fabsf(xd)));
  stv(out, idx, sp);
  stv(out, NBHW + idx,    ld(sxP, idx) + 0.1f*dot[1]);
  stv(out, 2L*NBHW + idx, ld(syP, idx) + 0.1f*dot[2]);
  float cf = dot[3] + 2.f*ld(confP, idx) - 1.f;
  stv(out, 19L*NBHW + idx, 1.f/(1.f + __expf(-cf)));
  #pragma unroll
  for (int r = 0; r < 16; ++r) {
    long fi = ((long)(b*16 + r))*HWP + p;
    stv(out, 3L*NBHW + fi, ld(featP, fi) + dot[4+r]);
  }
}

extern "C" void kernel_launch(void* const* d_in, const int* in_sizes, int n_in,
                              void* d_out, int out_size, void* d_ws, size_t ws_size,
                              hipStream_t stream)
{
  // workspace (~89 MiB): xpk (68.8 MB, fL+warp+cost) shares memory with h2
  char* ws = (char*)d_ws;
  size_t off = 0;
  u16* xpk = (u16*)(ws + off); off += (size_t)NSLAB*HWP*8*sizeof(u16); // 68.8 MB (xpk, later h2)
  u16* h1  = (u16*)(ws + off); off += (size_t)HID*HWP*sizeof(u16);     // 19.66 MB (h1, later h3)
  u16* wf1 = (u16*)(ws + off); off += (size_t)6*9*3*64*8*sizeof(u16);
  u16* wf2 = (u16*)(ws + off); off += (size_t)2*9*3*64*8*sizeof(u16);
  u16* wf3 = (u16*)(ws + off); off += (size_t)2*9*3*64*8*sizeof(u16);
  float* wh = (float*)(ws + off); off += (size_t)20*HID*sizeof(float);
  float* bh = (float*)(ws + off); off += 32*sizeof(float);
  float* st = (float*)(ws + off); off += 96*sizeof(float);
  int* flag = (int*)(ws + off);   off += sizeof(int);
  u16* h2 = xpk;    // reuse: xpk dead after conv1 of each batch
  u16* h3 = h1;     // reuse: h1 dead after conv2

  hipMemsetAsync(st, 0, 96*sizeof(float), stream);
  probe_k<<<1, 256, 0, stream>>>((const u16*)d_in[0], flag);

  dim3 cgrid(Wd/16, Hd/16, 1);

  #define LAUNCH_ALL(T) do { \
    const T* dP    = (const T*)d_in[0]; \
    const T* sxP   = (const T*)d_in[1]; \
    const T* syP   = (const T*)d_in[2]; \
    const T* featP = (const T*)d_in[3]; \
    const T* confP = (const T*)d_in[4]; \
    const T* fL    = (const T*)d_in[5]; \
    const T* fR    = (const T*)d_in[6]; \
    wconv_k<T><<<320, 256, 0, stream>>>(flag, (const T*)d_in[7], (const T*)d_in[8], \
        (const T*)d_in[9], (const T*)d_in[16], (const T*)d_in[17], (const T*)d_in[18], \
        (const T*)d_in[19], (const T*)d_in[20], (const T*)d_in[21], (const T*)d_in[22], \
        (const T*)d_in[23], (const T*)d_in[24], (const T*)d_in[25], wf1, wf2, wf3, wh, bh); \
    for (int b = 0; b < Bn; ++b) { \
      build_x_k<T><<<Hd, 640, 0, stream>>>(flag, b, dP, fL, fR, xpk); \
      conv1m_k<T><<<cgrid, 256, 0, stream>>>(flag, b, featP, dP, sxP, syP, confP, xpk, wf1, h1, st + 0); \
      convHm_k<T><<<cgrid, 256, 0, stream>>>(flag, b, h1, wf2, st + 0,  (const T*)d_in[10], (const T*)d_in[11], h2, st + 32); \
      convHm_k<T><<<cgrid, 256, 0, stream>>>(flag, b, h2, wf3, st + 32, (const T*)d_in[12], (const T*)d_in[13], h3, st + 64); \
      heads_k<T><<<HWP/256, 256, 0, stream>>>(flag, b, h3, st + 64, (const T*)d_in[14], (const T*)d_in[15], \
          wh, bh, dP, sxP, syP, featP, confP, (T*)d_out); \
    } \
  } while (0)

  LAUNCH_ALL(bf16);
  LAUNCH_ALL(float);
  #undef LAUNCH_ALL
}